// Round 12
// baseline (271.927 us; speedup 1.0000x reference)
//
#include <hip/hip_runtime.h>
#include <hip/hip_bf16.h>
#include <math.h>

#define HEADS 8
#define CH    512
#define S     1024
#define NKV   320
#define DH    64
#define BATCH 32

typedef __attribute__((ext_vector_type(8))) short short8;
typedef __attribute__((ext_vector_type(4))) short short4v;
typedef __attribute__((ext_vector_type(4))) float float4v;
typedef __attribute__((ext_vector_type(4))) unsigned int uint4v;

__device__ __forceinline__ short f2bf(float f) {
    __hip_bfloat16 h = __float2bfloat16(f);
    return *reinterpret_cast<short*>(&h);
}

__device__ __forceinline__ float fexp2(float x) {
#if __has_builtin(__builtin_amdgcn_exp2f)
    return __builtin_amdgcn_exp2f(x);
#else
    return exp2f(x);
#endif
}

// async global->LDS DMA, 16B/lane. LDS base must be wave-uniform; HW adds lane*16.
#define GLOAD_LDS16(gp, lp) __builtin_amdgcn_global_load_lds( \
    (const __attribute__((address_space(1))) void*)(gp),      \
    (__attribute__((address_space(3))) void*)(lp), 16, 0, 0)

// ---------------------------------------------------------------------------
// Fused transpose-cast + pooling: x [B,512,32,32] f32 read ONCE.
//   - xT[b][s][c] bf16 (transpose-cast, as before)
//   - xpT rows n=2bx,2bx+1 (th: mean over w) and n=64+bx*16+pw (tp: 2x2 pool)
//     written directly (this block's h-pair fully determines them)
//   - tw (mean over h) partials: atomicAdd f32 into twbuf[b][c][w] (2 MB,
//     L2-resident; zeroed by castw2; finalized by twfin)
// grid (16 s-tiles, 8 ch-tiles, B). Replaces pool_kernel2 + tcast: -64 MB HBM.
// ---------------------------------------------------------------------------
__global__ __launch_bounds__(256) void tcast2(const float* __restrict__ x,
                                              short* __restrict__ xT,
                                              short* __restrict__ xpT,
                                              float* __restrict__ twbuf) {
    __shared__ float sm[64][65];
    const int t = threadIdx.x;
    const int s0 = blockIdx.x * 64, ch0 = blockIdx.y * 64, b = blockIdx.z;
    const int hp = blockIdx.x;                 // pooled row pair {2hp, 2hp+1}
    const float* ib = x + ((size_t)b * 512 + ch0) * 1024 + s0;
    #pragma unroll
    for (int rep = 0; rep < 4; ++rep) {
        const int r = rep * 16 + (t >> 4), c = (t & 15) * 4;
        const float4 v = *(const float4*)&ib[(size_t)r * 1024 + c];
        sm[r][c] = v.x; sm[r][c + 1] = v.y; sm[r][c + 2] = v.z; sm[r][c + 3] = v.w;
    }
    __syncthreads();
    // ---- transpose-cast to xT[b][s][c] (identical to old tcast) ----
    short* ob = xT + ((size_t)b * 1024 + s0) * 512 + ch0;
    #pragma unroll
    for (int rep = 0; rep < 4; ++rep) {
        const int sr = rep * 16 + (t >> 4), cc = (t & 15) * 4;
        short4v p;
        #pragma unroll
        for (int e = 0; e < 4; ++e) p[e] = f2bf(sm[cc + e][sr]);
        *(short4v*)&ob[(size_t)sr * 512 + cc] = p;
    }
    // ---- th: rows n = 2hp, 2hp+1 (mean over w within each h row) ----
    if (t < 128) {
        const int r = t >> 1, half = t & 1;
        float s = 0.f;
        #pragma unroll
        for (int i = 0; i < 32; ++i) s += sm[r][half * 32 + i];
        xpT[((size_t)b * NKV + 2 * hp + half) * 512 + ch0 + r] = f2bf(s * (1.0f / 32.0f));
    }
    // ---- tp: rows n = 64 + hp*16 + pw (2x2 average pool) ----
    {
        const int r = t >> 2, pwq = (t & 3) * 4;
        #pragma unroll
        for (int k = 0; k < 4; ++k) {
            const int pw = pwq + k;
            const float v = 0.25f * (sm[r][2 * pw] + sm[r][2 * pw + 1] +
                                     sm[r][32 + 2 * pw] + sm[r][32 + 2 * pw + 1]);
            xpT[((size_t)b * NKV + 64 + hp * 16 + pw) * 512 + ch0 + r] = f2bf(v);
        }
    }
    // ---- tw partials: this block's 2 h-rows into twbuf[b][c][w] ----
    {
        const int w = t & 31, rb = (t >> 5) * 8;
        #pragma unroll
        for (int k = 0; k < 8; ++k) {
            const int r = rb + k;
            atomicAdd(&twbuf[((size_t)b * 512 + ch0 + r) * 32 + w],
                      sm[r][w] + sm[r][32 + w]);
        }
    }
}

// ---------------------------------------------------------------------------
// tw finalize: xpT[b][32+w][c] = bf16(twbuf[b][c][w] / 32). One block per b;
// coalesced twbuf reads, transpose via padded LDS, coalesced bf16 row writes.
// ---------------------------------------------------------------------------
__global__ __launch_bounds__(256) void twfin(const float* __restrict__ twbuf,
                                             short* __restrict__ xpT) {
    __shared__ short lds[32 * 514];
    const int b = blockIdx.x, t = threadIdx.x;
    #pragma unroll
    for (int i = 0; i < 64; ++i) {
        const int j = i * 256 + t;            // j over [512 c][32 w]
        const int c = j >> 5, w = j & 31;
        lds[w * 514 + c] = f2bf(twbuf[(size_t)b * 16384 + j] * (1.0f / 32.0f));
    }
    __syncthreads();
    short* dst = xpT + ((size_t)b * NKV + 32) * 512;
    #pragma unroll
    for (int rr = 0; rr < 32; ++rr) {
        const unsigned int v =
            (unsigned int)(unsigned short)lds[rr * 514 + t * 2] |
            ((unsigned int)(unsigned short)lds[rr * 514 + t * 2 + 1] << 16);
        *(unsigned int*)&dst[(size_t)rr * 512 + t * 2] = v;
    }
}

// ---------------------------------------------------------------------------
// Merged weight cast + twbuf zero: Wqkv -> oa (first nscale elems scaled by
// log2e), Wout -> ob; every thread also zeroes 16B of twbuf (runs before
// tcast2 on the stream, so the atomics accumulate onto 0).
// ---------------------------------------------------------------------------
__global__ __launch_bounds__(256) void castw2(const float* __restrict__ a,
                                              short* __restrict__ oa, int na, int nscale,
                                              const float* __restrict__ b,
                                              short* __restrict__ ob, int nb,
                                              float* __restrict__ twbuf) {
    const int gid = blockIdx.x * 256 + threadIdx.x;
    const int i = gid * 4;
    if (gid < 131072) {       // 131072*4 f32 = 2 MB
        const float4 z = {0.f, 0.f, 0.f, 0.f};
        ((float4*)twbuf)[gid] = z;
    }
    if (i < na) {
        const float sc = (i < nscale) ? 1.4426950408889634f : 1.0f;
        const float4 v = *(const float4*)&a[i];
        short4v p = {f2bf(v.x * sc), f2bf(v.y * sc), f2bf(v.z * sc), f2bf(v.w * sc)};
        *(short4v*)&oa[i] = p;
    } else if (i - na < nb) {
        const int j = i - na;
        const float4 v = *(const float4*)&b[j];
        short4v p = {f2bf(v.x), f2bf(v.y), f2bf(v.z), f2bf(v.w)};
        *(short4v*)&ob[j] = p;
    }
}

// ---------------------------------------------------------------------------
// GEMM body (R9-verified): 2-phase double-buffer, BK=64, XOR-swizzled packed
// LDS rows, 4 waves (2x2), wave tile (MT*16)x(NT*16). As/Bs carved from a
// caller-provided LDS arena (2*BM*64 + 2*BN*64 shorts).
// ACT: 0 none(bf16), 1 sigmoid+0.125 on col<512(bf16), 2 +bias[row](f32).
// ---------------------------------------------------------------------------
template <int MT, int NT, int ACT, typename OT>
__device__ __forceinline__ void gemm_body(short* __restrict__ smem,
                                          int bxs, int bys, int bz,
                                          const short* __restrict__ A, long sAb,
                                          const short* __restrict__ B, long sBb,
                                          const float* __restrict__ bias,
                                          OT* __restrict__ C, int M, int N) {
    constexpr int K  = 512;
    constexpr int BM = 32 * MT, BN = 32 * NT;
    short* As = smem;                       // [2][BM*64]
    short* Bs = smem + 2 * BM * 64;         // [2][BN*64]
    const int t = threadIdx.x, w = t >> 6, l = t & 63;
    const int wm = w >> 1, wn = w & 1, quad = l >> 4, m15 = l & 15;
    const int n0 = bxs * BN, m0 = bys * BM;
    const short* gA = A + (size_t)sAb * bz + (size_t)m0 * K;
    const short* gB = B + (size_t)sBb * bz + (size_t)n0 * K;
    const int lrow = l >> 3;     // row within an 8-row staging group
    const int pc   = l & 7;      // physical 16B chunk within row

    const float4v zf = {0.f, 0.f, 0.f, 0.f};
    float4v acc[MT][NT];
    #pragma unroll
    for (int i = 0; i < MT; ++i)
        #pragma unroll
        for (int j = 0; j < NT; ++j) acc[i][j] = zf;

    auto STAGE = [&](int bf, int k0) {
        #pragma unroll
        for (int ii = w; ii < BM / 8; ii += 4) {
            const int row = ii * 8 + lrow;
            const int x = pc ^ (row & 7);
            GLOAD_LDS16(gA + (size_t)row * K + k0 + x * 8, &As[bf * BM * 64 + ii * 512]);
        }
        #pragma unroll
        for (int ii = w; ii < BN / 8; ii += 4) {
            const int row = ii * 8 + lrow;
            const int x = pc ^ (row & 7);
            GLOAD_LDS16(gB + (size_t)row * K + k0 + x * 8, &Bs[bf * BN * 64 + ii * 512]);
        }
    };

    STAGE(0, 0);
    __syncthreads();
    for (int ks8 = 0; ks8 < 8; ++ks8) {
        const int cur = ks8 & 1;
        if (ks8 < 7) STAGE(cur ^ 1, (ks8 + 1) * 64);   // prefetch flies under MFMA
        #pragma unroll
        for (int ks = 0; ks < 2; ++ks) {
            const int xa = (((ks * 4 + quad) ^ (m15 & 7))) * 8;
            short8 aF[MT], bF[NT];
            #pragma unroll
            for (int i = 0; i < MT; ++i)
                aF[i] = *(const short8*)&As[cur * BM * 64 + ((wm * MT + i) * 16 + m15) * 64 + xa];
            #pragma unroll
            for (int j = 0; j < NT; ++j)
                bF[j] = *(const short8*)&Bs[cur * BN * 64 + ((wn * NT + j) * 16 + m15) * 64 + xa];
            #pragma unroll
            for (int i = 0; i < MT; ++i)
                #pragma unroll
                for (int j = 0; j < NT; ++j)
                    acc[i][j] = __builtin_amdgcn_mfma_f32_16x16x32_bf16(aF[i], bF[j], acc[i][j], 0, 0, 0);
        }
        if (ks8 < 7) __syncthreads();
    }

    OT* gC = C + (size_t)bz * M * N;
    #pragma unroll
    for (int i = 0; i < MT; ++i) {
        #pragma unroll
        for (int r = 0; r < 4; ++r) {
            const int row = m0 + (wm * MT + i) * 16 + quad * 4 + r;
            float bv = 0.f;
            if (ACT == 2) bv = bias[row];
            #pragma unroll
            for (int j = 0; j < NT; ++j) {
                const int col = n0 + (wn * NT + j) * 16 + m15;
                float v = acc[i][j][r];
                if (ACT == 1) { v = 1.0f / (1.0f + __expf(-v)); if (col < 512) v *= 0.125f; }
                if (ACT == 2) v += bv;
                if constexpr (sizeof(OT) == 2)
                    ((short*)gC)[(size_t)row * N + col] = f2bf(v);
                else
                    ((float*)gC)[(size_t)row * N + col] = v;
            }
        }
    }
}

// ---------------------------------------------------------------------------
// Merged Q + KV projection launch (R11-verified): 1664 blocks = 1024 GEMM1
// tiles (qT = xT.Wq) + 640 GEMM2 tiles (kvT = sigmoid(xpT.Wkv)). XCD swizzle
// over the combined index; role branch is block-uniform; 81920 B arena.
// ---------------------------------------------------------------------------
__global__ __launch_bounds__(256) void gemm_qkv(const short* __restrict__ xT,
                                                const short* __restrict__ Wq,
                                                const short* __restrict__ xpT,
                                                const short* __restrict__ Wkv,
                                                short* __restrict__ qT,
                                                short* __restrict__ kvT) {
    __shared__ short smem[40960];   // 81920 B arena
    constexpr int T = 1664;
    int lin = blockIdx.x;
    lin = (lin & 7) * (T >> 3) + (lin >> 3);
    if (lin < 1024) {
        const int bxs = lin & 3, bys = (lin >> 2) & 7, bz = lin >> 5;
        gemm_body<4, 4, 0, short>(smem, bxs, bys, bz,
                                  xT, (long)S * CH, Wq, 0, nullptr, qT, S, CH);
    } else {
        const int l2 = lin - 1024;
        const int bxs = l2 & 3, bys = (l2 >> 2) % 5, bz = l2 / 20;
        gemm_body<2, 8, 1, short>(smem, bxs, bys, bz,
                                  xpT, (long)NKV * CH, Wkv, 0, nullptr, kvT, NKV, 2 * CH);
    }
}

// ---------------------------------------------------------------------------
// Standalone GEMM (R9-verified) for the output projection.
// ---------------------------------------------------------------------------
template <int MT, int NT, int ACT, typename OT>
__global__ __launch_bounds__(256) void gemm_bf16(const short* __restrict__ A, long sAb,
                                                 const short* __restrict__ B, long sBb,
                                                 const float* __restrict__ bias,
                                                 OT* __restrict__ C, int M, int N) {
    constexpr int BM = 32 * MT, BN = 32 * NT;
    __shared__ short smem[2 * (BM + BN) * 64];
    const int gx = gridDim.x, gy = gridDim.y;
    const int T = gx * gy * gridDim.z;
    int lin = ((int)blockIdx.z * gy + (int)blockIdx.y) * gx + (int)blockIdx.x;
    lin = (lin & 7) * (T >> 3) + (lin >> 3);
    const int bxs = lin % gx;
    const int bys = (lin / gx) % gy;
    const int bz  = lin / (gx * gy);
    gemm_body<MT, NT, ACT, OT>(smem, bxs, bys, bz, A, sAb, B, sBb, bias, C, M, N);
}

// ---------------------------------------------------------------------------
// MFMA attention, v6 (FROZEN — verified 64 µs, FETCH 39.5 MB, 0 conflicts).
// ---------------------------------------------------------------------------
__global__ __launch_bounds__(512, 4) void attn_mfma(const short* __restrict__ qT,
                                                    const short* __restrict__ kvT,
                                                    const float* __restrict__ pos,
                                                    short* __restrict__ aoT) {
    __shared__ short smK[8 * 320 * 8];   // 40960 B: K packed [dg][n][8]
    __shared__ short smV[64 * 320];      // 40960 B: V^T [d][chunk x^(d&7)][8]
    const int tid = threadIdx.x, w = tid >> 6, l = tid & 63;
    const int quad = l >> 4, m15 = l & 15;
    const int b = blockIdx.z, h = blockIdx.y, s0 = blockIdx.x * 512;
    const short* kvb = kvT + (size_t)b * NKV * 1024;
    constexpr float LOG2E = 1.4426950408889634f;

    // ---- stage K, sigma-permuted rows: n_off = 32*l5+16*l3+8*l2+4*l4+2*l1+l0
    const int nperm = (l & 35) | ((l & 12) << 1) | ((l & 16) >> 2);
    #pragma unroll
    for (int i2 = w; i2 < 40; i2 += 8) {
        const int nb = i2 % 5, dg = i2 / 5;
        GLOAD_LDS16(kvb + (size_t)(nb * 64 + nperm) * 1024 + h * 64 + dg * 8,
                    &smK[(dg * 320 + nb * 64) * 8]);
    }
    // ---- V-half global->reg->LDS scatter (overlaps the K DMA in flight) ----
    #pragma unroll
    for (int it = 0; it < 5; ++it) {
        const int i2 = it * 512 + tid;
        const int n5 = i2 & 31, d8 = (i2 >> 5) & 7, nb = i2 >> 8;
        const int n = nb * 32 + n5;
        const short8 v = *(const short8*)&kvb[(size_t)n * 1024 + 512 + h * 64 + d8 * 8];
        const int x = n >> 3;
        #pragma unroll
        for (int e = 0; e < 8; ++e)
            smV[(d8 * 8 + e) * 320 + ((x ^ e) * 8) + (n & 7)] = v[e];
    }

    __syncthreads();   // the ONLY barrier: K DMA + V scatter complete

    const short* qbase = qT + (size_t)(b * S + s0 + w * 16 + m15) * 512 + h * 64;
    const float4v zf = {0.f, 0.f, 0.f, 0.f};

    #pragma unroll 1
    for (int sp = 0; sp < 2; ++sp) {
        // Anti-LICM: LDS "may have changed" across the backedge -> smK/smV
        // fragment loads cannot be hoisted out (the v3/v4 spill failure mode).
        asm volatile("" ::: "memory");

        const short* qbA = qbase + (size_t)(2 * sp) * 128 * 512;
        const short* qbB = qbA + (size_t)128 * 512;
        const short8 cqA0 = *(const short8*)&qbA[quad * 8];
        const short8 cqA1 = *(const short8*)&qbA[32 + quad * 8];
        const short8 cqB0 = *(const short8*)&qbB[quad * 8];
        const short8 cqB1 = *(const short8*)&qbB[32 + quad * 8];
        const float* posA = pos + (size_t)(s0 + 2 * sp * 128 + w * 16 + m15) * NKV + quad * 8;
        const float* posB = posA + (size_t)128 * NKV;

        float4v OA0 = zf, OA1 = zf, OA2 = zf, OA3 = zf;
        float4v OB0 = zf, OB1 = zf, OB2 = zf, OB3 = zf;
        float lpA = 0.f, lpB = 0.f;

        #pragma unroll
        for (int c = 0; c < 5; ++c) {
            unsigned int PcA[8], PcB[8];
            // ---- 4 score tiles x 2 s-tiles: shared K-frag reads ----
            #pragma unroll
            for (int t4 = 0; t4 < 4; ++t4) {
                const int tt = c * 4 + t4;
                const short8 k0 = *(const short8*)&smK[(quad * 320 + tt * 16 + m15) * 8];
                const short8 k1 = *(const short8*)&smK[((4 + quad) * 320 + tt * 16 + m15) * 8];
                float4v aA = zf, aB = zf;
                aA = __builtin_amdgcn_mfma_f32_16x16x32_bf16(k0, cqA0, aA, 0, 0, 0);
                aA = __builtin_amdgcn_mfma_f32_16x16x32_bf16(k1, cqA1, aA, 0, 0, 0);
                aB = __builtin_amdgcn_mfma_f32_16x16x32_bf16(k0, cqB0, aB, 0, 0, 0);
                aB = __builtin_amdgcn_mfma_f32_16x16x32_bf16(k1, cqB1, aB, 0, 0, 0);
                const int n0 = c * 64 + (t4 >> 1) * 32 + (t4 & 1) * 4;
                const float4 pvA = *(const float4*)&posA[n0];
                const float4 pvB = *(const float4*)&posB[n0];
                const float a0 = fexp2(fmaf(pvA.x, LOG2E, aA[0]));
                const float a1 = fexp2(fmaf(pvA.y, LOG2E, aA[1]));
                const float a2 = fexp2(fmaf(pvA.z, LOG2E, aA[2]));
                const float a3 = fexp2(fmaf(pvA.w, LOG2E, aA[3]));
                const float b0 = fexp2(fmaf(pvB.x, LOG2E, aB[0]));
                const float b1 = fexp2(fmaf(pvB.y, LOG2E, aB[1]));
                const float b2 = fexp2(fmaf(pvB.z, LOG2E, aB[2]));
                const float b3 = fexp2(fmaf(pvB.w, LOG2E, aB[3]));
                lpA += (a0 + a1) + (a2 + a3);
                lpB += (b0 + b1) + (b2 + b3);
                PcA[t4 * 2]     = (unsigned int)(unsigned short)f2bf(a0) |
                                  ((unsigned int)(unsigned short)f2bf(a1) << 16);
                PcA[t4 * 2 + 1] = (unsigned int)(unsigned short)f2bf(a2) |
                                  ((unsigned int)(unsigned short)f2bf(a3) << 16);
                PcB[t4 * 2]     = (unsigned int)(unsigned short)f2bf(b0) |
                                  ((unsigned int)(unsigned short)f2bf(b1) << 16);
                PcB[t4 * 2 + 1] = (unsigned int)(unsigned short)f2bf(b2) |
                                  ((unsigned int)(unsigned short)f2bf(b3) << 16);
            }
            // ---- PV for both tiles: shared V-frag reads ----
            const uint4v uA0 = {PcA[0], PcA[1], PcA[2], PcA[3]};
            const uint4v uA1 = {PcA[4], PcA[5], PcA[6], PcA[7]};
            const uint4v uB0 = {PcB[0], PcB[1], PcB[2], PcB[3]};
            const uint4v uB1 = {PcB[4], PcB[5], PcB[6], PcB[7]};
            const short8 aPA0 = __builtin_bit_cast(short8, uA0);
            const short8 aPA1 = __builtin_bit_cast(short8, uA1);
            const short8 aPB0 = __builtin_bit_cast(short8, uB0);
            const short8 aPB1 = __builtin_bit_cast(short8, uB1);
            #pragma unroll
            for (int ks = 0; ks < 2; ++ks) {
                const short8 aPA = ks ? aPA1 : aPA0;
                const short8 aPB = ks ? aPB1 : aPB0;
                const int xr = (c * 8 + ks * 4 + quad) ^ (m15 & 7);
                const short8 bV0 = *(const short8*)&smV[(0 * 16 + m15) * 320 + xr * 8];
                const short8 bV1 = *(const short8*)&smV[(1 * 16 + m15) * 320 + xr * 8];
                const short8 bV2 = *(const short8*)&smV[(2 * 16 + m15) * 320 + xr * 8];
                const short8 bV3 = *(const short8*)&smV[(3 * 16 + m15) * 320 + xr * 8];
                OA0 = __builtin_amdgcn_mfma_f32_16x16x32_bf16(aPA, bV0, OA0, 0, 0, 0);
                OB0 = __builtin_amdgcn_mfma_f32_16x16x32_bf16(aPB, bV0, OB0, 0, 0, 0);
                OA1 = __builtin_amdgcn_mfma_f32_16x16x32_bf16(aPA, bV1, OA1, 0, 0, 0);
                OB1 = __builtin_amdgcn_mfma_f32_16x16x32_bf16(aPB, bV1, OB1, 0, 0, 0);
                OA2 = __builtin_amdgcn_mfma_f32_16x16x32_bf16(aPA, bV2, OA2, 0, 0, 0);
                OB2 = __builtin_amdgcn_mfma_f32_16x16x32_bf16(aPB, bV2, OB2, 0, 0, 0);
                OA3 = __builtin_amdgcn_mfma_f32_16x16x32_bf16(aPA, bV3, OA3, 0, 0, 0);
                OB3 = __builtin_amdgcn_mfma_f32_16x16x32_bf16(aPB, bV3, OB3, 0, 0, 0);
            }
        }

        // ---- row sums (each quad holds a disjoint n-subset) ----
        float lrA = lpA, lrB = lpB;
        lrA += __shfl_xor(lrA, 16, 64);
        lrA += __shfl_xor(lrA, 32, 64);
        lrB += __shfl_xor(lrB, 16, 64);
        lrB += __shfl_xor(lrB, 32, 64);
        const float invlA = 1.0f / lrA;
        const float invlB = 1.0f / lrB;
        float invA[4], invB[4];
        #pragma unroll
        for (int r = 0; r < 4; ++r) {
            invA[r] = __shfl(invlA, (l & 48) | (quad * 4 + r), 64);
            invB[r] = __shfl(invlB, (l & 48) | (quad * 4 + r), 64);
        }

        // ---- normalize + direct bf16 output aoT[b][s][c] ----
        #pragma unroll
        for (int r = 0; r < 4; ++r) {
            const int sA = s0 + 2 * sp * 128 + w * 16 + quad * 4 + r;
            short* orA = &aoT[(size_t)(b * S + sA) * 512 + h * 64 + m15];
            orA[0]  = f2bf(OA0[r] * invA[r]);
            orA[16] = f2bf(OA1[r] * invA[r]);
            orA[32] = f2bf(OA2[r] * invA[r]);
            orA[48] = f2bf(OA3[r] * invA[r]);
            short* orB = orA + (size_t)128 * 512;
            orB[0]  = f2bf(OB0[r] * invB[r]);
            orB[16] = f2bf(OB1[r] * invB[r]);
            orB[32] = f2bf(OB2[r] * invB[r]);
            orB[48] = f2bf(OB3[r] * invB[r]);
        }
    }
}

// ---------------------------------------------------------------------------
extern "C" void kernel_launch(void* const* d_in, const int* in_sizes, int n_in,
                              void* d_out, int out_size, void* d_ws, size_t ws_size,
                              hipStream_t stream) {
    const float* x    = (const float*)d_in[0];
    const float* Wqkv = (const float*)d_in[1];
    const float* Wout = (const float*)d_in[2];
    const float* bout = (const float*)d_in[3];
    const float* pos  = (const float*)d_in[4];
    char* ws = (char*)d_ws;
    float* twbuf = (float*)(ws + 0);           // [32][512][32] f32     2097152 B
    short* xT   = (short*)(ws + 20971520);     // [32][1024][512] bf16 33554432 B
    short* xpT  = (short*)(ws + 54525952);     // [32][320][512] bf16  10485760 B
    short* qT   = (short*)(ws + 65011712);     // [32][1024][512] bf16 33554432 B
    short* kvT  = (short*)(ws + 98566144);     // [32][320][1024] bf16 20971520 B
    short* aoT  = (short*)(ws + 119537664);    // [32][1024][512] bf16 33554432 B
    short* Wbf  = (short*)(ws + 153092096);    // [1536][512] bf16      1572864 B
    short* Wobf = (short*)(ws + 154664960);    // [512][512] bf16        524288 B
    float* out  = (float*)d_out;

    // Wq rows pre-scaled by log2e; also zeroes twbuf (before tcast2's atomics)
    castw2<<<dim3(1024), 256, 0, stream>>>(Wqkv, Wbf, 1536 * 512, 512 * 512,
                                           Wout, Wobf, 512 * 512, twbuf);
    // x read ONCE: xT transpose-cast + th/tp pooled rows + tw atomic partials
    tcast2<<<dim3(16, 8, BATCH), 256, 0, stream>>>(x, xT, xpT, twbuf);
    // finalize tw rows (n = 32..63) of xpT
    twfin<<<dim3(BATCH), 256, 0, stream>>>(twbuf, xpT);
    // merged: qT = xT.(Wq*log2e)  AND  kvT = sigmoid(xpT.Wkv) (k pre-scaled 0.125)
    gemm_qkv<<<dim3(1664), 256, 0, stream>>>(xT, Wbf, xpT, Wbf + CH * CH, qT, kvT);
    attn_mfma<<<dim3(2, HEADS, BATCH), 512, 0, stream>>>(qT, kvT, pos, aoT);
    // out[b][c][s] = Wout . aoT + bout  (fp32, direct coalesced)
    gemm_bf16<4, 4, 2, float><<<dim3(8, 4, BATCH), 256, 0, stream>>>(
        Wobf, 0, aoT, (long)S * CH, bout, out, CH, S);
}

// Round 13
// 264.337 us; speedup vs baseline: 1.0287x; 1.0287x over previous
//
#include <hip/hip_runtime.h>
#include <hip/hip_bf16.h>
#include <math.h>

#define HEADS 8
#define CH    512
#define S     1024
#define NKV   320
#define DH    64
#define BATCH 32

typedef __attribute__((ext_vector_type(8))) short short8;
typedef __attribute__((ext_vector_type(4))) short short4v;
typedef __attribute__((ext_vector_type(4))) float float4v;
typedef __attribute__((ext_vector_type(4))) unsigned int uint4v;

__device__ __forceinline__ short f2bf(float f) {
    __hip_bfloat16 h = __float2bfloat16(f);
    return *reinterpret_cast<short*>(&h);
}

__device__ __forceinline__ float fexp2(float x) {
#if __has_builtin(__builtin_amdgcn_exp2f)
    return __builtin_amdgcn_exp2f(x);
#else
    return exp2f(x);
#endif
}

// async global->LDS DMA, 16B/lane. LDS base must be wave-uniform; HW adds lane*16.
#define GLOAD_LDS16(gp, lp) __builtin_amdgcn_global_load_lds( \
    (const __attribute__((address_space(1))) void*)(gp),      \
    (__attribute__((address_space(3))) void*)(lp), 16, 0, 0)

// ---------------------------------------------------------------------------
// Fused pool+transpose+cast: x [B,C,32,32] f32 -> xpT [B,320,512] bf16.
// ---------------------------------------------------------------------------
__global__ __launch_bounds__(256) void pool_kernel2(const float* __restrict__ x,
                                                    short* __restrict__ xpT) {
    __shared__ float sm[4][1024];
    __shared__ short smT[320 * 34];
    const int w = threadIdx.x >> 6;
    const int l = threadIdx.x & 63;
    const int b = blockIdx.y, c0 = blockIdx.x * 32;
    for (int it = 0; it < 8; ++it) {
        const int cix = it * 4 + w;
        const float* src = x + ((size_t)b * 512 + c0 + cix) * 1024;
        #pragma unroll
        for (int j = 0; j < 16; ++j) sm[w][j * 64 + l] = src[j * 64 + l];
        const float* pl = sm[w];     // wave-private: in-wave lgkm ordering suffices
        #pragma unroll
        for (int g = 0; g < 5; ++g) {
            const int nn = g * 64 + l;
            float r;
            if (nn < 32) {
                const int h = nn; float s = 0.f;
                #pragma unroll
                for (int ww = 0; ww < 32; ++ww) s += pl[h * 32 + ww];
                r = s * (1.0f / 32.0f);
            } else if (nn < 64) {
                const int ww = nn - 32; float s = 0.f;
                #pragma unroll
                for (int h = 0; h < 32; ++h) s += pl[h * 32 + ww];
                r = s * (1.0f / 32.0f);
            } else {
                const int i = nn - 64;
                const int ph = i >> 4, pw = i & 15;
                r = 0.25f * (pl[(2 * ph) * 32 + 2 * pw]     + pl[(2 * ph) * 32 + 2 * pw + 1] +
                             pl[(2 * ph + 1) * 32 + 2 * pw] + pl[(2 * ph + 1) * 32 + 2 * pw + 1]);
            }
            smT[nn * 34 + cix] = f2bf(r);
        }
    }
    __syncthreads();
    short* dst = xpT + (size_t)b * NKV * 512 + c0;
    const int r0 = threadIdx.x >> 4, dwi = threadIdx.x & 15;
    #pragma unroll
    for (int pass = 0; pass < 20; ++pass) {
        const int r = pass * 16 + r0;
        const unsigned int v =
            (unsigned int)(unsigned short)smT[r * 34 + dwi * 2] |
            ((unsigned int)(unsigned short)smT[r * 34 + dwi * 2 + 1] << 16);
        *(unsigned int*)&dst[(size_t)r * 512 + dwi * 2] = v;
    }
}

// ---------------------------------------------------------------------------
// Transpose-cast: in [bz][R][C] fp32 -> out [bz][C][R] bf16. grid (C/64, R/64, B)
// ---------------------------------------------------------------------------
__global__ __launch_bounds__(256) void tcast(const float* __restrict__ in,
                                             short* __restrict__ out, int R, int C) {
    __shared__ float sm[64][65];
    const int t = threadIdx.x;
    const int c0 = blockIdx.x * 64, r0 = blockIdx.y * 64;
    const float* ib = in + ((size_t)blockIdx.z * R + r0) * C + c0;
    #pragma unroll
    for (int rep = 0; rep < 4; ++rep) {
        const int r = rep * 16 + (t >> 4), c = (t & 15) * 4;
        const float4 v = *(const float4*)&ib[(size_t)r * C + c];
        sm[r][c] = v.x; sm[r][c + 1] = v.y; sm[r][c + 2] = v.z; sm[r][c + 3] = v.w;
    }
    __syncthreads();
    short* ob = out + ((size_t)blockIdx.z * C + c0) * R + r0;
    #pragma unroll
    for (int rep = 0; rep < 4; ++rep) {
        const int cr = rep * 16 + (t >> 4), rc = (t & 15) * 4;
        short4v p;
        #pragma unroll
        for (int e = 0; e < 4; ++e) p[e] = f2bf(sm[rc + e][cr]);
        *(short4v*)&ob[(size_t)cr * R + rc] = p;
    }
}

// ---------------------------------------------------------------------------
// Merged weight cast: Wqkv -> oa (first nscale elems scaled by log2e), Wout -> ob.
// ---------------------------------------------------------------------------
__global__ __launch_bounds__(256) void castw2(const float* __restrict__ a,
                                              short* __restrict__ oa, int na, int nscale,
                                              const float* __restrict__ b,
                                              short* __restrict__ ob, int nb) {
    const int i = (blockIdx.x * 256 + threadIdx.x) * 4;
    if (i < na) {
        const float sc = (i < nscale) ? 1.4426950408889634f : 1.0f;
        const float4 v = *(const float4*)&a[i];
        short4v p = {f2bf(v.x * sc), f2bf(v.y * sc), f2bf(v.z * sc), f2bf(v.w * sc)};
        *(short4v*)&oa[i] = p;
    } else if (i - na < nb) {
        const int j = i - na;
        const float4 v = *(const float4*)&b[j];
        short4v p = {f2bf(v.x), f2bf(v.y), f2bf(v.z), f2bf(v.w)};
        *(short4v*)&ob[j] = p;
    }
}

// ---------------------------------------------------------------------------
// GEMM body (R9-verified): 2-phase double-buffer, BK=64, XOR-swizzled packed
// LDS rows, 4 waves (2x2), wave tile (MT*16)x(NT*16). As/Bs carved from a
// caller-provided LDS arena (2*BM*64 + 2*BN*64 shorts).
// ACT: 0 none(bf16), 1 sigmoid+0.125 on col<512(bf16), 2 +bias[row](f32).
// ---------------------------------------------------------------------------
template <int MT, int NT, int ACT, typename OT>
__device__ __forceinline__ void gemm_body(short* __restrict__ smem,
                                          int bxs, int bys, int bz,
                                          const short* __restrict__ A, long sAb,
                                          const short* __restrict__ B, long sBb,
                                          const float* __restrict__ bias,
                                          OT* __restrict__ C, int M, int N) {
    constexpr int K  = 512;
    constexpr int BM = 32 * MT, BN = 32 * NT;
    short* As = smem;                       // [2][BM*64]
    short* Bs = smem + 2 * BM * 64;         // [2][BN*64]
    const int t = threadIdx.x, w = t >> 6, l = t & 63;
    const int wm = w >> 1, wn = w & 1, quad = l >> 4, m15 = l & 15;
    const int n0 = bxs * BN, m0 = bys * BM;
    const short* gA = A + (size_t)sAb * bz + (size_t)m0 * K;
    const short* gB = B + (size_t)sBb * bz + (size_t)n0 * K;
    const int lrow = l >> 3;     // row within an 8-row staging group
    const int pc   = l & 7;      // physical 16B chunk within row

    const float4v zf = {0.f, 0.f, 0.f, 0.f};
    float4v acc[MT][NT];
    #pragma unroll
    for (int i = 0; i < MT; ++i)
        #pragma unroll
        for (int j = 0; j < NT; ++j) acc[i][j] = zf;

    auto STAGE = [&](int bf, int k0) {
        #pragma unroll
        for (int ii = w; ii < BM / 8; ii += 4) {
            const int row = ii * 8 + lrow;
            const int x = pc ^ (row & 7);
            GLOAD_LDS16(gA + (size_t)row * K + k0 + x * 8, &As[bf * BM * 64 + ii * 512]);
        }
        #pragma unroll
        for (int ii = w; ii < BN / 8; ii += 4) {
            const int row = ii * 8 + lrow;
            const int x = pc ^ (row & 7);
            GLOAD_LDS16(gB + (size_t)row * K + k0 + x * 8, &Bs[bf * BN * 64 + ii * 512]);
        }
    };

    STAGE(0, 0);
    __syncthreads();
    for (int ks8 = 0; ks8 < 8; ++ks8) {
        const int cur = ks8 & 1;
        if (ks8 < 7) STAGE(cur ^ 1, (ks8 + 1) * 64);   // prefetch flies under MFMA
        #pragma unroll
        for (int ks = 0; ks < 2; ++ks) {
            const int xa = (((ks * 4 + quad) ^ (m15 & 7))) * 8;
            short8 aF[MT], bF[NT];
            #pragma unroll
            for (int i = 0; i < MT; ++i)
                aF[i] = *(const short8*)&As[cur * BM * 64 + ((wm * MT + i) * 16 + m15) * 64 + xa];
            #pragma unroll
            for (int j = 0; j < NT; ++j)
                bF[j] = *(const short8*)&Bs[cur * BN * 64 + ((wn * NT + j) * 16 + m15) * 64 + xa];
            #pragma unroll
            for (int i = 0; i < MT; ++i)
                #pragma unroll
                for (int j = 0; j < NT; ++j)
                    acc[i][j] = __builtin_amdgcn_mfma_f32_16x16x32_bf16(aF[i], bF[j], acc[i][j], 0, 0, 0);
        }
        if (ks8 < 7) __syncthreads();
    }

    OT* gC = C + (size_t)bz * M * N;
    #pragma unroll
    for (int i = 0; i < MT; ++i) {
        #pragma unroll
        for (int r = 0; r < 4; ++r) {
            const int row = m0 + (wm * MT + i) * 16 + quad * 4 + r;
            float bv = 0.f;
            if (ACT == 2) bv = bias[row];
            #pragma unroll
            for (int j = 0; j < NT; ++j) {
                const int col = n0 + (wn * NT + j) * 16 + m15;
                float v = acc[i][j][r];
                if (ACT == 1) { v = 1.0f / (1.0f + __expf(-v)); if (col < 512) v *= 0.125f; }
                if (ACT == 2) v += bv;
                if constexpr (sizeof(OT) == 2)
                    ((short*)gC)[(size_t)row * N + col] = f2bf(v);
                else
                    ((float*)gC)[(size_t)row * N + col] = v;
            }
        }
    }
}

// ---------------------------------------------------------------------------
// Merged Q + KV projection launch (R11-verified): 1664 blocks = 1024 GEMM1
// tiles (qT = xT.Wq) + 640 GEMM2 tiles (kvT = sigmoid(xpT.Wkv)). XCD swizzle
// over the combined index; role branch is block-uniform; 81920 B arena.
// ---------------------------------------------------------------------------
__global__ __launch_bounds__(256) void gemm_qkv(const short* __restrict__ xT,
                                                const short* __restrict__ Wq,
                                                const short* __restrict__ xpT,
                                                const short* __restrict__ Wkv,
                                                short* __restrict__ qT,
                                                short* __restrict__ kvT) {
    __shared__ short smem[40960];   // 81920 B arena
    constexpr int T = 1664;
    int lin = blockIdx.x;
    lin = (lin & 7) * (T >> 3) + (lin >> 3);
    if (lin < 1024) {
        const int bxs = lin & 3, bys = (lin >> 2) & 7, bz = lin >> 5;
        gemm_body<4, 4, 0, short>(smem, bxs, bys, bz,
                                  xT, (long)S * CH, Wq, 0, nullptr, qT, S, CH);
    } else {
        const int l2 = lin - 1024;
        const int bxs = l2 & 3, bys = (l2 >> 2) % 5, bz = l2 / 20;
        gemm_body<2, 8, 1, short>(smem, bxs, bys, bz,
                                  xpT, (long)NKV * CH, Wkv, 0, nullptr, kvT, NKV, 2 * CH);
    }
}

// ---------------------------------------------------------------------------
// Standalone GEMM (R9-verified) for the output projection.
// ---------------------------------------------------------------------------
template <int MT, int NT, int ACT, typename OT>
__global__ __launch_bounds__(256) void gemm_bf16(const short* __restrict__ A, long sAb,
                                                 const short* __restrict__ B, long sBb,
                                                 const float* __restrict__ bias,
                                                 OT* __restrict__ C, int M, int N) {
    constexpr int BM = 32 * MT, BN = 32 * NT;
    __shared__ short smem[2 * (BM + BN) * 64];
    const int gx = gridDim.x, gy = gridDim.y;
    const int T = gx * gy * gridDim.z;
    int lin = ((int)blockIdx.z * gy + (int)blockIdx.y) * gx + (int)blockIdx.x;
    lin = (lin & 7) * (T >> 3) + (lin >> 3);
    const int bxs = lin % gx;
    const int bys = (lin / gx) % gy;
    const int bz  = lin / (gx * gy);
    gemm_body<MT, NT, ACT, OT>(smem, bxs, bys, bz, A, sAb, B, sBb, bias, C, M, N);
}

// ---------------------------------------------------------------------------
// MFMA attention, v7 = v6 (verified 64 µs, FETCH 39.5 MB, 0 conflicts) +
// T5 s_setprio(1) around the QK and PV MFMA clusters. Mechanism (m191): after
// the single barrier, 8 waves drift freely through interleaved MFMA/VALU
// phases; setprio biases the CU scheduler toward matrix-pipe-feeding waves
// while others run softmax VALU. Pure scheduler hint, no correctness impact.
// ---------------------------------------------------------------------------
__global__ __launch_bounds__(512, 4) void attn_mfma(const short* __restrict__ qT,
                                                    const short* __restrict__ kvT,
                                                    const float* __restrict__ pos,
                                                    short* __restrict__ aoT) {
    __shared__ short smK[8 * 320 * 8];   // 40960 B: K packed [dg][n][8]
    __shared__ short smV[64 * 320];      // 40960 B: V^T [d][chunk x^(d&7)][8]
    const int tid = threadIdx.x, w = tid >> 6, l = tid & 63;
    const int quad = l >> 4, m15 = l & 15;
    const int b = blockIdx.z, h = blockIdx.y, s0 = blockIdx.x * 512;
    const short* kvb = kvT + (size_t)b * NKV * 1024;
    constexpr float LOG2E = 1.4426950408889634f;

    // ---- stage K, sigma-permuted rows: n_off = 32*l5+16*l3+8*l2+4*l4+2*l1+l0
    const int nperm = (l & 35) | ((l & 12) << 1) | ((l & 16) >> 2);
    #pragma unroll
    for (int i2 = w; i2 < 40; i2 += 8) {
        const int nb = i2 % 5, dg = i2 / 5;
        GLOAD_LDS16(kvb + (size_t)(nb * 64 + nperm) * 1024 + h * 64 + dg * 8,
                    &smK[(dg * 320 + nb * 64) * 8]);
    }
    // ---- V-half global->reg->LDS scatter (overlaps the K DMA in flight) ----
    #pragma unroll
    for (int it = 0; it < 5; ++it) {
        const int i2 = it * 512 + tid;
        const int n5 = i2 & 31, d8 = (i2 >> 5) & 7, nb = i2 >> 8;
        const int n = nb * 32 + n5;
        const short8 v = *(const short8*)&kvb[(size_t)n * 1024 + 512 + h * 64 + d8 * 8];
        const int x = n >> 3;
        #pragma unroll
        for (int e = 0; e < 8; ++e)
            smV[(d8 * 8 + e) * 320 + ((x ^ e) * 8) + (n & 7)] = v[e];
    }

    __syncthreads();   // the ONLY barrier: K DMA + V scatter complete

    const short* qbase = qT + (size_t)(b * S + s0 + w * 16 + m15) * 512 + h * 64;
    const float4v zf = {0.f, 0.f, 0.f, 0.f};

    #pragma unroll 1
    for (int sp = 0; sp < 2; ++sp) {
        // Anti-LICM: LDS "may have changed" across the backedge -> smK/smV
        // fragment loads cannot be hoisted out (the v3/v4 spill failure mode).
        asm volatile("" ::: "memory");

        const short* qbA = qbase + (size_t)(2 * sp) * 128 * 512;
        const short* qbB = qbA + (size_t)128 * 512;
        const short8 cqA0 = *(const short8*)&qbA[quad * 8];
        const short8 cqA1 = *(const short8*)&qbA[32 + quad * 8];
        const short8 cqB0 = *(const short8*)&qbB[quad * 8];
        const short8 cqB1 = *(const short8*)&qbB[32 + quad * 8];
        const float* posA = pos + (size_t)(s0 + 2 * sp * 128 + w * 16 + m15) * NKV + quad * 8;
        const float* posB = posA + (size_t)128 * NKV;

        float4v OA0 = zf, OA1 = zf, OA2 = zf, OA3 = zf;
        float4v OB0 = zf, OB1 = zf, OB2 = zf, OB3 = zf;
        float lpA = 0.f, lpB = 0.f;

        #pragma unroll
        for (int c = 0; c < 5; ++c) {
            unsigned int PcA[8], PcB[8];
            // ---- 4 score tiles x 2 s-tiles: shared K-frag reads ----
            #pragma unroll
            for (int t4 = 0; t4 < 4; ++t4) {
                const int tt = c * 4 + t4;
                const short8 k0 = *(const short8*)&smK[(quad * 320 + tt * 16 + m15) * 8];
                const short8 k1 = *(const short8*)&smK[((4 + quad) * 320 + tt * 16 + m15) * 8];
                float4v aA = zf, aB = zf;
                __builtin_amdgcn_s_setprio(1);
                aA = __builtin_amdgcn_mfma_f32_16x16x32_bf16(k0, cqA0, aA, 0, 0, 0);
                aA = __builtin_amdgcn_mfma_f32_16x16x32_bf16(k1, cqA1, aA, 0, 0, 0);
                aB = __builtin_amdgcn_mfma_f32_16x16x32_bf16(k0, cqB0, aB, 0, 0, 0);
                aB = __builtin_amdgcn_mfma_f32_16x16x32_bf16(k1, cqB1, aB, 0, 0, 0);
                __builtin_amdgcn_s_setprio(0);
                const int n0 = c * 64 + (t4 >> 1) * 32 + (t4 & 1) * 4;
                const float4 pvA = *(const float4*)&posA[n0];
                const float4 pvB = *(const float4*)&posB[n0];
                const float a0 = fexp2(fmaf(pvA.x, LOG2E, aA[0]));
                const float a1 = fexp2(fmaf(pvA.y, LOG2E, aA[1]));
                const float a2 = fexp2(fmaf(pvA.z, LOG2E, aA[2]));
                const float a3 = fexp2(fmaf(pvA.w, LOG2E, aA[3]));
                const float b0 = fexp2(fmaf(pvB.x, LOG2E, aB[0]));
                const float b1 = fexp2(fmaf(pvB.y, LOG2E, aB[1]));
                const float b2 = fexp2(fmaf(pvB.z, LOG2E, aB[2]));
                const float b3 = fexp2(fmaf(pvB.w, LOG2E, aB[3]));
                lpA += (a0 + a1) + (a2 + a3);
                lpB += (b0 + b1) + (b2 + b3);
                PcA[t4 * 2]     = (unsigned int)(unsigned short)f2bf(a0) |
                                  ((unsigned int)(unsigned short)f2bf(a1) << 16);
                PcA[t4 * 2 + 1] = (unsigned int)(unsigned short)f2bf(a2) |
                                  ((unsigned int)(unsigned short)f2bf(a3) << 16);
                PcB[t4 * 2]     = (unsigned int)(unsigned short)f2bf(b0) |
                                  ((unsigned int)(unsigned short)f2bf(b1) << 16);
                PcB[t4 * 2 + 1] = (unsigned int)(unsigned short)f2bf(b2) |
                                  ((unsigned int)(unsigned short)f2bf(b3) << 16);
            }
            // ---- PV for both tiles: shared V-frag reads ----
            const uint4v uA0 = {PcA[0], PcA[1], PcA[2], PcA[3]};
            const uint4v uA1 = {PcA[4], PcA[5], PcA[6], PcA[7]};
            const uint4v uB0 = {PcB[0], PcB[1], PcB[2], PcB[3]};
            const uint4v uB1 = {PcB[4], PcB[5], PcB[6], PcB[7]};
            const short8 aPA0 = __builtin_bit_cast(short8, uA0);
            const short8 aPA1 = __builtin_bit_cast(short8, uA1);
            const short8 aPB0 = __builtin_bit_cast(short8, uB0);
            const short8 aPB1 = __builtin_bit_cast(short8, uB1);
            #pragma unroll
            for (int ks = 0; ks < 2; ++ks) {
                const short8 aPA = ks ? aPA1 : aPA0;
                const short8 aPB = ks ? aPB1 : aPB0;
                const int xr = (c * 8 + ks * 4 + quad) ^ (m15 & 7);
                const short8 bV0 = *(const short8*)&smV[(0 * 16 + m15) * 320 + xr * 8];
                const short8 bV1 = *(const short8*)&smV[(1 * 16 + m15) * 320 + xr * 8];
                const short8 bV2 = *(const short8*)&smV[(2 * 16 + m15) * 320 + xr * 8];
                const short8 bV3 = *(const short8*)&smV[(3 * 16 + m15) * 320 + xr * 8];
                __builtin_amdgcn_s_setprio(1);
                OA0 = __builtin_amdgcn_mfma_f32_16x16x32_bf16(aPA, bV0, OA0, 0, 0, 0);
                OB0 = __builtin_amdgcn_mfma_f32_16x16x32_bf16(aPB, bV0, OB0, 0, 0, 0);
                OA1 = __builtin_amdgcn_mfma_f32_16x16x32_bf16(aPA, bV1, OA1, 0, 0, 0);
                OB1 = __builtin_amdgcn_mfma_f32_16x16x32_bf16(aPB, bV1, OB1, 0, 0, 0);
                OA2 = __builtin_amdgcn_mfma_f32_16x16x32_bf16(aPA, bV2, OA2, 0, 0, 0);
                OB2 = __builtin_amdgcn_mfma_f32_16x16x32_bf16(aPB, bV2, OB2, 0, 0, 0);
                OA3 = __builtin_amdgcn_mfma_f32_16x16x32_bf16(aPA, bV3, OA3, 0, 0, 0);
                OB3 = __builtin_amdgcn_mfma_f32_16x16x32_bf16(aPB, bV3, OB3, 0, 0, 0);
                __builtin_amdgcn_s_setprio(0);
            }
        }

        // ---- row sums (each quad holds a disjoint n-subset) ----
        float lrA = lpA, lrB = lpB;
        lrA += __shfl_xor(lrA, 16, 64);
        lrA += __shfl_xor(lrA, 32, 64);
        lrB += __shfl_xor(lrB, 16, 64);
        lrB += __shfl_xor(lrB, 32, 64);
        const float invlA = 1.0f / lrA;
        const float invlB = 1.0f / lrB;
        float invA[4], invB[4];
        #pragma unroll
        for (int r = 0; r < 4; ++r) {
            invA[r] = __shfl(invlA, (l & 48) | (quad * 4 + r), 64);
            invB[r] = __shfl(invlB, (l & 48) | (quad * 4 + r), 64);
        }

        // ---- normalize + direct bf16 output aoT[b][s][c] ----
        #pragma unroll
        for (int r = 0; r < 4; ++r) {
            const int sA = s0 + 2 * sp * 128 + w * 16 + quad * 4 + r;
            short* orA = &aoT[(size_t)(b * S + sA) * 512 + h * 64 + m15];
            orA[0]  = f2bf(OA0[r] * invA[r]);
            orA[16] = f2bf(OA1[r] * invA[r]);
            orA[32] = f2bf(OA2[r] * invA[r]);
            orA[48] = f2bf(OA3[r] * invA[r]);
            short* orB = orA + (size_t)128 * 512;
            orB[0]  = f2bf(OB0[r] * invB[r]);
            orB[16] = f2bf(OB1[r] * invB[r]);
            orB[32] = f2bf(OB2[r] * invB[r]);
            orB[48] = f2bf(OB3[r] * invB[r]);
        }
    }
}

// ---------------------------------------------------------------------------
extern "C" void kernel_launch(void* const* d_in, const int* in_sizes, int n_in,
                              void* d_out, int out_size, void* d_ws, size_t ws_size,
                              hipStream_t stream) {
    const float* x    = (const float*)d_in[0];
    const float* Wqkv = (const float*)d_in[1];
    const float* Wout = (const float*)d_in[2];
    const float* bout = (const float*)d_in[3];
    const float* pos  = (const float*)d_in[4];
    char* ws = (char*)d_ws;
    short* xT   = (short*)(ws + 20971520);     // [32][1024][512] bf16 33554432 B
    short* xpT  = (short*)(ws + 54525952);     // [32][320][512] bf16  10485760 B
    short* qT   = (short*)(ws + 65011712);     // [32][1024][512] bf16 33554432 B
    short* kvT  = (short*)(ws + 98566144);     // [32][320][1024] bf16 20971520 B
    short* aoT  = (short*)(ws + 119537664);    // [32][1024][512] bf16 33554432 B
    short* Wbf  = (short*)(ws + 153092096);    // [1536][512] bf16      1572864 B
    short* Wobf = (short*)(ws + 154664960);    // [512][512] bf16        524288 B
    float* out  = (float*)d_out;

    // Wq rows pre-scaled by log2e (exp2-softmax fold)
    castw2<<<dim3(1024), 256, 0, stream>>>(Wqkv, Wbf, 1536 * 512, 512 * 512,
                                           Wout, Wobf, 512 * 512);
    pool_kernel2<<<dim3(16, BATCH), 256, 0, stream>>>(x, xpT);         // -> xpT [n][c]
    tcast<<<dim3(16, 8, BATCH), 256, 0, stream>>>(x, xT, CH, S);       // -> xT [s][c]
    // merged: qT = xT.(Wq*log2e)  AND  kvT = sigmoid(xpT.Wkv) (k pre-scaled 0.125)
    gemm_qkv<<<dim3(1664), 256, 0, stream>>>(xT, Wbf, xpT, Wbf + CH * CH, qT, kvT);
    attn_mfma<<<dim3(2, HEADS, BATCH), 512, 0, stream>>>(qT, kvT, pos, aoT);
    // out[b][c][s] = Wout . aoT + bout  (fp32, direct coalesced)
    gemm_bf16<4, 4, 2, float><<<dim3(8, 4, BATCH), 256, 0, stream>>>(
        Wobf, 0, aoT, (long)S * CH, bout, out, CH, S);
}

// Round 14
// 257.157 us; speedup vs baseline: 1.0574x; 1.0279x over previous
//
#include <hip/hip_runtime.h>
#include <hip/hip_bf16.h>
#include <math.h>

#define HEADS 8
#define CH    512
#define S     1024
#define NKV   320
#define DH    64
#define BATCH 32

typedef __attribute__((ext_vector_type(8))) short short8;
typedef __attribute__((ext_vector_type(4))) short short4v;
typedef __attribute__((ext_vector_type(4))) float float4v;
typedef __attribute__((ext_vector_type(4))) unsigned int uint4v;

__device__ __forceinline__ short f2bf(float f) {
    __hip_bfloat16 h = __float2bfloat16(f);
    return *reinterpret_cast<short*>(&h);
}

__device__ __forceinline__ float fexp2(float x) {
#if __has_builtin(__builtin_amdgcn_exp2f)
    return __builtin_amdgcn_exp2f(x);
#else
    return exp2f(x);
#endif
}

// async global->LDS DMA, 16B/lane. LDS base must be wave-uniform; HW adds lane*16.
#define GLOAD_LDS16(gp, lp) __builtin_amdgcn_global_load_lds( \
    (const __attribute__((address_space(1))) void*)(gp),      \
    (__attribute__((address_space(3))) void*)(lp), 16, 0, 0)

// ---------------------------------------------------------------------------
// Merged prep kernel: 5632 blocks, block-uniform role branch.
//   [0,4096):   tcast role  — x [b][ch][s] f32 -> xT [b][s][ch] bf16
//   [4096,4608): pool role  — x -> xpT [b][320][512] bf16 (th|tw|tp)
//   [4608,5632): castw role — Wqkv -> Wbf (Wq rows *log2e), Wout -> Wobf
// Roles are independent; merging removes 2 launch gaps and overlaps tails.
// LDS arena 38144 B (max role) -> 4 blocks/CU. Bodies identical to the
// R13-verified standalone kernels.
// ---------------------------------------------------------------------------
__global__ __launch_bounds__(256) void prep(const float* __restrict__ x,
                                            short* __restrict__ xT,
                                            short* __restrict__ xpT,
                                            const float* __restrict__ Wqkv,
                                            short* __restrict__ Wbf,
                                            const float* __restrict__ Wout,
                                            short* __restrict__ Wobf) {
    __shared__ float arena[9536];   // 38144 B
    const int lin = blockIdx.x, t = threadIdx.x;
    if (lin < 4096) {
        // ---- tcast role: R=512 (channels), C=1024 (spatial) ----
        float (*sm)[65] = (float(*)[65])arena;  // 64x65 f32 = 16640 B
        const int c0 = (lin & 15) * 64, r0 = ((lin >> 4) & 7) * 64, bz = lin >> 7;
        const float* ib = x + ((size_t)bz * 512 + r0) * 1024 + c0;
        #pragma unroll
        for (int rep = 0; rep < 4; ++rep) {
            const int r = rep * 16 + (t >> 4), c = (t & 15) * 4;
            const float4 v = *(const float4*)&ib[(size_t)r * 1024 + c];
            sm[r][c] = v.x; sm[r][c + 1] = v.y; sm[r][c + 2] = v.z; sm[r][c + 3] = v.w;
        }
        __syncthreads();
        short* ob = xT + ((size_t)bz * 1024 + c0) * 512 + r0;
        #pragma unroll
        for (int rep = 0; rep < 4; ++rep) {
            const int cr = rep * 16 + (t >> 4), rc = (t & 15) * 4;
            short4v p;
            #pragma unroll
            for (int e = 0; e < 4; ++e) p[e] = f2bf(sm[rc + e][cr]);
            *(short4v*)&ob[(size_t)cr * 512 + rc] = p;
        }
    } else if (lin < 4608) {
        // ---- pool role ----
        float* smf = arena;                       // [4][1024] f32 = 16384 B
        short* smT = (short*)(arena + 4096);      // 320*34 bf16  = 21760 B
        const int l2 = lin - 4096;
        const int w = t >> 6, l = t & 63;
        const int b = l2 >> 4, c0 = (l2 & 15) * 32;
        for (int it = 0; it < 8; ++it) {
            const int cix = it * 4 + w;
            const float* src = x + ((size_t)b * 512 + c0 + cix) * 1024;
            #pragma unroll
            for (int j = 0; j < 16; ++j) smf[w * 1024 + j * 64 + l] = src[j * 64 + l];
            const float* pl = &smf[w * 1024];   // wave-private
            #pragma unroll
            for (int g = 0; g < 5; ++g) {
                const int nn = g * 64 + l;
                float r;
                if (nn < 32) {
                    const int h = nn; float s = 0.f;
                    #pragma unroll
                    for (int ww = 0; ww < 32; ++ww) s += pl[h * 32 + ww];
                    r = s * (1.0f / 32.0f);
                } else if (nn < 64) {
                    const int ww = nn - 32; float s = 0.f;
                    #pragma unroll
                    for (int h = 0; h < 32; ++h) s += pl[h * 32 + ww];
                    r = s * (1.0f / 32.0f);
                } else {
                    const int i = nn - 64;
                    const int ph = i >> 4, pw = i & 15;
                    r = 0.25f * (pl[(2 * ph) * 32 + 2 * pw]     + pl[(2 * ph) * 32 + 2 * pw + 1] +
                                 pl[(2 * ph + 1) * 32 + 2 * pw] + pl[(2 * ph + 1) * 32 + 2 * pw + 1]);
                }
                smT[nn * 34 + cix] = f2bf(r);
            }
        }
        __syncthreads();
        short* dst = xpT + (size_t)b * NKV * 512 + c0;
        const int r0 = t >> 4, dwi = t & 15;
        #pragma unroll
        for (int pass = 0; pass < 20; ++pass) {
            const int r = pass * 16 + r0;
            const unsigned int v =
                (unsigned int)(unsigned short)smT[r * 34 + dwi * 2] |
                ((unsigned int)(unsigned short)smT[r * 34 + dwi * 2 + 1] << 16);
            *(unsigned int*)&dst[(size_t)r * 512 + dwi * 2] = v;
        }
    } else {
        // ---- castw role: na=786432 (nscale=262144 Wq elems *log2e), nb=262144
        const int i = ((lin - 4608) * 256 + t) * 4;
        constexpr int na = 1536 * 512, nscale = 512 * 512, nb = 512 * 512;
        if (i < na) {
            const float sc = (i < nscale) ? 1.4426950408889634f : 1.0f;
            const float4 v = *(const float4*)&Wqkv[i];
            short4v p = {f2bf(v.x * sc), f2bf(v.y * sc), f2bf(v.z * sc), f2bf(v.w * sc)};
            *(short4v*)&Wbf[i] = p;
        } else if (i - na < nb) {
            const int j = i - na;
            const float4 v = *(const float4*)&Wout[j];
            short4v p = {f2bf(v.x), f2bf(v.y), f2bf(v.z), f2bf(v.w)};
            *(short4v*)&Wobf[j] = p;
        }
    }
}

// ---------------------------------------------------------------------------
// GEMM body (R9-verified): 2-phase double-buffer, BK=64, XOR-swizzled packed
// LDS rows, 4 waves (2x2), wave tile (MT*16)x(NT*16). As/Bs carved from a
// caller-provided LDS arena (2*BM*64 + 2*BN*64 shorts).
// ACT: 0 none(bf16), 1 sigmoid+0.125 on col<512(bf16), 2 +bias[row](f32).
// ---------------------------------------------------------------------------
template <int MT, int NT, int ACT, typename OT>
__device__ __forceinline__ void gemm_body(short* __restrict__ smem,
                                          int bxs, int bys, int bz,
                                          const short* __restrict__ A, long sAb,
                                          const short* __restrict__ B, long sBb,
                                          const float* __restrict__ bias,
                                          OT* __restrict__ C, int M, int N) {
    constexpr int K  = 512;
    constexpr int BM = 32 * MT, BN = 32 * NT;
    short* As = smem;                       // [2][BM*64]
    short* Bs = smem + 2 * BM * 64;         // [2][BN*64]
    const int t = threadIdx.x, w = t >> 6, l = t & 63;
    const int wm = w >> 1, wn = w & 1, quad = l >> 4, m15 = l & 15;
    const int n0 = bxs * BN, m0 = bys * BM;
    const short* gA = A + (size_t)sAb * bz + (size_t)m0 * K;
    const short* gB = B + (size_t)sBb * bz + (size_t)n0 * K;
    const int lrow = l >> 3;     // row within an 8-row staging group
    const int pc   = l & 7;      // physical 16B chunk within row

    const float4v zf = {0.f, 0.f, 0.f, 0.f};
    float4v acc[MT][NT];
    #pragma unroll
    for (int i = 0; i < MT; ++i)
        #pragma unroll
        for (int j = 0; j < NT; ++j) acc[i][j] = zf;

    auto STAGE = [&](int bf, int k0) {
        #pragma unroll
        for (int ii = w; ii < BM / 8; ii += 4) {
            const int row = ii * 8 + lrow;
            const int x = pc ^ (row & 7);
            GLOAD_LDS16(gA + (size_t)row * K + k0 + x * 8, &As[bf * BM * 64 + ii * 512]);
        }
        #pragma unroll
        for (int ii = w; ii < BN / 8; ii += 4) {
            const int row = ii * 8 + lrow;
            const int x = pc ^ (row & 7);
            GLOAD_LDS16(gB + (size_t)row * K + k0 + x * 8, &Bs[bf * BN * 64 + ii * 512]);
        }
    };

    STAGE(0, 0);
    __syncthreads();
    for (int ks8 = 0; ks8 < 8; ++ks8) {
        const int cur = ks8 & 1;
        if (ks8 < 7) STAGE(cur ^ 1, (ks8 + 1) * 64);   // prefetch flies under MFMA
        #pragma unroll
        for (int ks = 0; ks < 2; ++ks) {
            const int xa = (((ks * 4 + quad) ^ (m15 & 7))) * 8;
            short8 aF[MT], bF[NT];
            #pragma unroll
            for (int i = 0; i < MT; ++i)
                aF[i] = *(const short8*)&As[cur * BM * 64 + ((wm * MT + i) * 16 + m15) * 64 + xa];
            #pragma unroll
            for (int j = 0; j < NT; ++j)
                bF[j] = *(const short8*)&Bs[cur * BN * 64 + ((wn * NT + j) * 16 + m15) * 64 + xa];
            #pragma unroll
            for (int i = 0; i < MT; ++i)
                #pragma unroll
                for (int j = 0; j < NT; ++j)
                    acc[i][j] = __builtin_amdgcn_mfma_f32_16x16x32_bf16(aF[i], bF[j], acc[i][j], 0, 0, 0);
        }
        if (ks8 < 7) __syncthreads();
    }

    OT* gC = C + (size_t)bz * M * N;
    #pragma unroll
    for (int i = 0; i < MT; ++i) {
        #pragma unroll
        for (int r = 0; r < 4; ++r) {
            const int row = m0 + (wm * MT + i) * 16 + quad * 4 + r;
            float bv = 0.f;
            if (ACT == 2) bv = bias[row];
            #pragma unroll
            for (int j = 0; j < NT; ++j) {
                const int col = n0 + (wn * NT + j) * 16 + m15;
                float v = acc[i][j][r];
                if (ACT == 1) { v = 1.0f / (1.0f + __expf(-v)); if (col < 512) v *= 0.125f; }
                if (ACT == 2) v += bv;
                if constexpr (sizeof(OT) == 2)
                    ((short*)gC)[(size_t)row * N + col] = f2bf(v);
                else
                    ((float*)gC)[(size_t)row * N + col] = v;
            }
        }
    }
}

// ---------------------------------------------------------------------------
// Merged Q + KV projection launch (R11-verified): 1664 blocks = 1024 GEMM1
// tiles (qT = xT.Wq) + 640 GEMM2 tiles (kvT = sigmoid(xpT.Wkv)). XCD swizzle
// over the combined index; role branch is block-uniform; 81920 B arena.
// ---------------------------------------------------------------------------
__global__ __launch_bounds__(256) void gemm_qkv(const short* __restrict__ xT,
                                                const short* __restrict__ Wq,
                                                const short* __restrict__ xpT,
                                                const short* __restrict__ Wkv,
                                                short* __restrict__ qT,
                                                short* __restrict__ kvT) {
    __shared__ short smem[40960];   // 81920 B arena
    constexpr int T = 1664;
    int lin = blockIdx.x;
    lin = (lin & 7) * (T >> 3) + (lin >> 3);
    if (lin < 1024) {
        const int bxs = lin & 3, bys = (lin >> 2) & 7, bz = lin >> 5;
        gemm_body<4, 4, 0, short>(smem, bxs, bys, bz,
                                  xT, (long)S * CH, Wq, 0, nullptr, qT, S, CH);
    } else {
        const int l2 = lin - 1024;
        const int bxs = l2 & 3, bys = (l2 >> 2) % 5, bz = l2 / 20;
        gemm_body<2, 8, 1, short>(smem, bxs, bys, bz,
                                  xpT, (long)NKV * CH, Wkv, 0, nullptr, kvT, NKV, 2 * CH);
    }
}

// ---------------------------------------------------------------------------
// Standalone GEMM (R9-verified) for the output projection.
// ---------------------------------------------------------------------------
template <int MT, int NT, int ACT, typename OT>
__global__ __launch_bounds__(256) void gemm_bf16(const short* __restrict__ A, long sAb,
                                                 const short* __restrict__ B, long sBb,
                                                 const float* __restrict__ bias,
                                                 OT* __restrict__ C, int M, int N) {
    constexpr int BM = 32 * MT, BN = 32 * NT;
    __shared__ short smem[2 * (BM + BN) * 64];
    const int gx = gridDim.x, gy = gridDim.y;
    const int T = gx * gy * gridDim.z;
    int lin = ((int)blockIdx.z * gy + (int)blockIdx.y) * gx + (int)blockIdx.x;
    lin = (lin & 7) * (T >> 3) + (lin >> 3);
    const int bxs = lin % gx;
    const int bys = (lin / gx) % gy;
    const int bz  = lin / (gx * gy);
    gemm_body<MT, NT, ACT, OT>(smem, bxs, bys, bz, A, sAb, B, sBb, bias, C, M, N);
}

// ---------------------------------------------------------------------------
// MFMA attention, v7 (R13-verified ~62 µs): v6 + T5 s_setprio around the QK
// and PV MFMA clusters (m191 mechanism: free-running waves after the single
// barrier -> scheduler biases matrix-pipe-feeding waves).
// ---------------------------------------------------------------------------
__global__ __launch_bounds__(512, 4) void attn_mfma(const short* __restrict__ qT,
                                                    const short* __restrict__ kvT,
                                                    const float* __restrict__ pos,
                                                    short* __restrict__ aoT) {
    __shared__ short smK[8 * 320 * 8];   // 40960 B: K packed [dg][n][8]
    __shared__ short smV[64 * 320];      // 40960 B: V^T [d][chunk x^(d&7)][8]
    const int tid = threadIdx.x, w = tid >> 6, l = tid & 63;
    const int quad = l >> 4, m15 = l & 15;
    const int b = blockIdx.z, h = blockIdx.y, s0 = blockIdx.x * 512;
    const short* kvb = kvT + (size_t)b * NKV * 1024;
    constexpr float LOG2E = 1.4426950408889634f;

    // ---- stage K, sigma-permuted rows: n_off = 32*l5+16*l3+8*l2+4*l4+2*l1+l0
    const int nperm = (l & 35) | ((l & 12) << 1) | ((l & 16) >> 2);
    #pragma unroll
    for (int i2 = w; i2 < 40; i2 += 8) {
        const int nb = i2 % 5, dg = i2 / 5;
        GLOAD_LDS16(kvb + (size_t)(nb * 64 + nperm) * 1024 + h * 64 + dg * 8,
                    &smK[(dg * 320 + nb * 64) * 8]);
    }
    // ---- V-half global->reg->LDS scatter (overlaps the K DMA in flight) ----
    #pragma unroll
    for (int it = 0; it < 5; ++it) {
        const int i2 = it * 512 + tid;
        const int n5 = i2 & 31, d8 = (i2 >> 5) & 7, nb = i2 >> 8;
        const int n = nb * 32 + n5;
        const short8 v = *(const short8*)&kvb[(size_t)n * 1024 + 512 + h * 64 + d8 * 8];
        const int x = n >> 3;
        #pragma unroll
        for (int e = 0; e < 8; ++e)
            smV[(d8 * 8 + e) * 320 + ((x ^ e) * 8) + (n & 7)] = v[e];
    }

    __syncthreads();   // the ONLY barrier: K DMA + V scatter complete

    const short* qbase = qT + (size_t)(b * S + s0 + w * 16 + m15) * 512 + h * 64;
    const float4v zf = {0.f, 0.f, 0.f, 0.f};

    #pragma unroll 1
    for (int sp = 0; sp < 2; ++sp) {
        // Anti-LICM: LDS "may have changed" across the backedge -> smK/smV
        // fragment loads cannot be hoisted out (the v3/v4 spill failure mode).
        asm volatile("" ::: "memory");

        const short* qbA = qbase + (size_t)(2 * sp) * 128 * 512;
        const short* qbB = qbA + (size_t)128 * 512;
        const short8 cqA0 = *(const short8*)&qbA[quad * 8];
        const short8 cqA1 = *(const short8*)&qbA[32 + quad * 8];
        const short8 cqB0 = *(const short8*)&qbB[quad * 8];
        const short8 cqB1 = *(const short8*)&qbB[32 + quad * 8];
        const float* posA = pos + (size_t)(s0 + 2 * sp * 128 + w * 16 + m15) * NKV + quad * 8;
        const float* posB = posA + (size_t)128 * NKV;

        float4v OA0 = zf, OA1 = zf, OA2 = zf, OA3 = zf;
        float4v OB0 = zf, OB1 = zf, OB2 = zf, OB3 = zf;
        float lpA = 0.f, lpB = 0.f;

        #pragma unroll
        for (int c = 0; c < 5; ++c) {
            unsigned int PcA[8], PcB[8];
            // ---- 4 score tiles x 2 s-tiles: shared K-frag reads ----
            #pragma unroll
            for (int t4 = 0; t4 < 4; ++t4) {
                const int tt = c * 4 + t4;
                const short8 k0 = *(const short8*)&smK[(quad * 320 + tt * 16 + m15) * 8];
                const short8 k1 = *(const short8*)&smK[((4 + quad) * 320 + tt * 16 + m15) * 8];
                float4v aA = zf, aB = zf;
                __builtin_amdgcn_s_setprio(1);
                aA = __builtin_amdgcn_mfma_f32_16x16x32_bf16(k0, cqA0, aA, 0, 0, 0);
                aA = __builtin_amdgcn_mfma_f32_16x16x32_bf16(k1, cqA1, aA, 0, 0, 0);
                aB = __builtin_amdgcn_mfma_f32_16x16x32_bf16(k0, cqB0, aB, 0, 0, 0);
                aB = __builtin_amdgcn_mfma_f32_16x16x32_bf16(k1, cqB1, aB, 0, 0, 0);
                __builtin_amdgcn_s_setprio(0);
                const int n0 = c * 64 + (t4 >> 1) * 32 + (t4 & 1) * 4;
                const float4 pvA = *(const float4*)&posA[n0];
                const float4 pvB = *(const float4*)&posB[n0];
                const float a0 = fexp2(fmaf(pvA.x, LOG2E, aA[0]));
                const float a1 = fexp2(fmaf(pvA.y, LOG2E, aA[1]));
                const float a2 = fexp2(fmaf(pvA.z, LOG2E, aA[2]));
                const float a3 = fexp2(fmaf(pvA.w, LOG2E, aA[3]));
                const float b0 = fexp2(fmaf(pvB.x, LOG2E, aB[0]));
                const float b1 = fexp2(fmaf(pvB.y, LOG2E, aB[1]));
                const float b2 = fexp2(fmaf(pvB.z, LOG2E, aB[2]));
                const float b3 = fexp2(fmaf(pvB.w, LOG2E, aB[3]));
                lpA += (a0 + a1) + (a2 + a3);
                lpB += (b0 + b1) + (b2 + b3);
                PcA[t4 * 2]     = (unsigned int)(unsigned short)f2bf(a0) |
                                  ((unsigned int)(unsigned short)f2bf(a1) << 16);
                PcA[t4 * 2 + 1] = (unsigned int)(unsigned short)f2bf(a2) |
                                  ((unsigned int)(unsigned short)f2bf(a3) << 16);
                PcB[t4 * 2]     = (unsigned int)(unsigned short)f2bf(b0) |
                                  ((unsigned int)(unsigned short)f2bf(b1) << 16);
                PcB[t4 * 2 + 1] = (unsigned int)(unsigned short)f2bf(b2) |
                                  ((unsigned int)(unsigned short)f2bf(b3) << 16);
            }
            // ---- PV for both tiles: shared V-frag reads ----
            const uint4v uA0 = {PcA[0], PcA[1], PcA[2], PcA[3]};
            const uint4v uA1 = {PcA[4], PcA[5], PcA[6], PcA[7]};
            const uint4v uB0 = {PcB[0], PcB[1], PcB[2], PcB[3]};
            const uint4v uB1 = {PcB[4], PcB[5], PcB[6], PcB[7]};
            const short8 aPA0 = __builtin_bit_cast(short8, uA0);
            const short8 aPA1 = __builtin_bit_cast(short8, uA1);
            const short8 aPB0 = __builtin_bit_cast(short8, uB0);
            const short8 aPB1 = __builtin_bit_cast(short8, uB1);
            #pragma unroll
            for (int ks = 0; ks < 2; ++ks) {
                const short8 aPA = ks ? aPA1 : aPA0;
                const short8 aPB = ks ? aPB1 : aPB0;
                const int xr = (c * 8 + ks * 4 + quad) ^ (m15 & 7);
                const short8 bV0 = *(const short8*)&smV[(0 * 16 + m15) * 320 + xr * 8];
                const short8 bV1 = *(const short8*)&smV[(1 * 16 + m15) * 320 + xr * 8];
                const short8 bV2 = *(const short8*)&smV[(2 * 16 + m15) * 320 + xr * 8];
                const short8 bV3 = *(const short8*)&smV[(3 * 16 + m15) * 320 + xr * 8];
                __builtin_amdgcn_s_setprio(1);
                OA0 = __builtin_amdgcn_mfma_f32_16x16x32_bf16(aPA, bV0, OA0, 0, 0, 0);
                OB0 = __builtin_amdgcn_mfma_f32_16x16x32_bf16(aPB, bV0, OB0, 0, 0, 0);
                OA1 = __builtin_amdgcn_mfma_f32_16x16x32_bf16(aPA, bV1, OA1, 0, 0, 0);
                OB1 = __builtin_amdgcn_mfma_f32_16x16x32_bf16(aPB, bV1, OB1, 0, 0, 0);
                OA2 = __builtin_amdgcn_mfma_f32_16x16x32_bf16(aPA, bV2, OA2, 0, 0, 0);
                OB2 = __builtin_amdgcn_mfma_f32_16x16x32_bf16(aPB, bV2, OB2, 0, 0, 0);
                OA3 = __builtin_amdgcn_mfma_f32_16x16x32_bf16(aPA, bV3, OA3, 0, 0, 0);
                OB3 = __builtin_amdgcn_mfma_f32_16x16x32_bf16(aPB, bV3, OB3, 0, 0, 0);
                __builtin_amdgcn_s_setprio(0);
            }
        }

        // ---- row sums (each quad holds a disjoint n-subset) ----
        float lrA = lpA, lrB = lpB;
        lrA += __shfl_xor(lrA, 16, 64);
        lrA += __shfl_xor(lrA, 32, 64);
        lrB += __shfl_xor(lrB, 16, 64);
        lrB += __shfl_xor(lrB, 32, 64);
        const float invlA = 1.0f / lrA;
        const float invlB = 1.0f / lrB;
        float invA[4], invB[4];
        #pragma unroll
        for (int r = 0; r < 4; ++r) {
            invA[r] = __shfl(invlA, (l & 48) | (quad * 4 + r), 64);
            invB[r] = __shfl(invlB, (l & 48) | (quad * 4 + r), 64);
        }

        // ---- normalize + direct bf16 output aoT[b][s][c] ----
        #pragma unroll
        for (int r = 0; r < 4; ++r) {
            const int sA = s0 + 2 * sp * 128 + w * 16 + quad * 4 + r;
            short* orA = &aoT[(size_t)(b * S + sA) * 512 + h * 64 + m15];
            orA[0]  = f2bf(OA0[r] * invA[r]);
            orA[16] = f2bf(OA1[r] * invA[r]);
            orA[32] = f2bf(OA2[r] * invA[r]);
            orA[48] = f2bf(OA3[r] * invA[r]);
            short* orB = orA + (size_t)128 * 512;
            orB[0]  = f2bf(OB0[r] * invB[r]);
            orB[16] = f2bf(OB1[r] * invB[r]);
            orB[32] = f2bf(OB2[r] * invB[r]);
            orB[48] = f2bf(OB3[r] * invB[r]);
        }
    }
}

// ---------------------------------------------------------------------------
extern "C" void kernel_launch(void* const* d_in, const int* in_sizes, int n_in,
                              void* d_out, int out_size, void* d_ws, size_t ws_size,
                              hipStream_t stream) {
    const float* x    = (const float*)d_in[0];
    const float* Wqkv = (const float*)d_in[1];
    const float* Wout = (const float*)d_in[2];
    const float* bout = (const float*)d_in[3];
    const float* pos  = (const float*)d_in[4];
    char* ws = (char*)d_ws;
    short* xT   = (short*)(ws + 20971520);     // [32][1024][512] bf16 33554432 B
    short* xpT  = (short*)(ws + 54525952);     // [32][320][512] bf16  10485760 B
    short* qT   = (short*)(ws + 65011712);     // [32][1024][512] bf16 33554432 B
    short* kvT  = (short*)(ws + 98566144);     // [32][320][1024] bf16 20971520 B
    short* aoT  = (short*)(ws + 119537664);    // [32][1024][512] bf16 33554432 B
    short* Wbf  = (short*)(ws + 153092096);    // [1536][512] bf16      1572864 B
    short* Wobf = (short*)(ws + 154664960);    // [512][512] bf16        524288 B
    float* out  = (float*)d_out;

    // merged prep: tcast (x->xT) + pool (x->xpT) + weight casts, one launch
    prep<<<dim3(5632), 256, 0, stream>>>(x, xT, xpT, Wqkv, Wbf, Wout, Wobf);
    // merged: qT = xT.(Wq*log2e)  AND  kvT = sigmoid(xpT.Wkv) (k pre-scaled 0.125)
    gemm_qkv<<<dim3(1664), 256, 0, stream>>>(xT, Wbf, xpT, Wbf + CH * CH, qT, kvT);
    attn_mfma<<<dim3(2, HEADS, BATCH), 512, 0, stream>>>(qT, kvT, pos, aoT);
    // out[b][c][s] = Wout . aoT + bout  (fp32, direct coalesced)
    gemm_bf16<4, 4, 2, float><<<dim3(8, 4, BATCH), 256, 0, stream>>>(
        Wobf, 0, aoT, (long)S * CH, bout, out, CH, S);
}